// Round 2
// baseline (251.765 us; speedup 1.0000x reference)
//
#include <hip/hip_runtime.h>

typedef __attribute__((ext_vector_type(8))) short short8;
typedef __attribute__((ext_vector_type(4))) float floatx4;

__device__ __forceinline__ unsigned short f2b(float f) {
    union { float f; unsigned int i; } v; v.f = f;
    unsigned int u = v.i;
    u += 0x7FFFu + ((u >> 16) & 1u);   // round-nearest-even; NaN impossible here
    return (unsigned short)(u >> 16);
}

// Block: 4 waves x 32 rows = 128 rows. Grid 2048 -> 262144 rows.
// W (128x128 fp32) staged as bf16 in LDS, row stride 136 shorts (272 B =
// 17*16 B: ds_read_b128 stays 16B-aligned; bank aliasing 2-way = free).
__global__ __launch_bounds__(256) void mobius_linear_kernel(
    const float* __restrict__ X,
    const float* __restrict__ W,
    const float* __restrict__ Bias,
    float* __restrict__ Out)
{
    __shared__ unsigned short ldsW[128 * 136];

    const int tid  = threadIdx.x;
    const int wave = tid >> 6;
    const int lane = tid & 63;
    const int q = lane >> 4;     // quad
    const int c = lane & 15;     // col-in-frag (B) / row-in-frag (A)

    // ---- stage W into LDS as bf16 (each thread: 8 chunks of 8 floats) ----
#pragma unroll
    for (int i = 0; i < 8; ++i) {
        int chunk = i * 256 + tid;          // 0..2047
        int row = chunk >> 4, cc = chunk & 15;
        const float* src = W + row * 128 + cc * 8;
        floatx4 w0 = *reinterpret_cast<const floatx4*>(src);
        floatx4 w1 = *reinterpret_cast<const floatx4*>(src + 4);
        short8 pk;
#pragma unroll
        for (int j = 0; j < 4; ++j) { pk[j] = (short)f2b(w0[j]); pk[4 + j] = (short)f2b(w1[j]); }
        *reinterpret_cast<short8*>(&ldsW[row * 136 + cc * 8]) = pk;
    }

    // ---- bias fragment (col = n*16 + c) and ||b||^2 ----
    float bias_f[8];
#pragma unroll
    for (int n = 0; n < 8; ++n) bias_f[n] = Bias[n * 16 + c];
    float b2 = 0.f;
#pragma unroll
    for (int n = 0; n < 8; ++n) b2 = fmaf(bias_f[n], bias_f[n], b2);
    b2 += __shfl_xor(b2, 1);
    b2 += __shfl_xor(b2, 2);
    b2 += __shfl_xor(b2, 4);
    b2 += __shfl_xor(b2, 8);

    const int rowbase = blockIdx.x * 128 + wave * 32;

    // ---- A fragments: load fp32, accumulate ||x||^2 in fp32, pack bf16 ----
    short8 afrag[2][4];
    float xn2[2] = {0.f, 0.f};
#pragma unroll
    for (int g = 0; g < 2; ++g) {
        const float* xrow = X + (size_t)(rowbase + g * 16 + c) * 128;
#pragma unroll
        for (int kc = 0; kc < 4; ++kc) {
            const float* src = xrow + kc * 32 + q * 8;
            floatx4 x0 = *reinterpret_cast<const floatx4*>(src);
            floatx4 x1 = *reinterpret_cast<const floatx4*>(src + 4);
            short8 pk;
#pragma unroll
            for (int j = 0; j < 4; ++j) {
                xn2[g] = fmaf(x0[j], x0[j], xn2[g]);
                xn2[g] = fmaf(x1[j], x1[j], xn2[g]);
                pk[j] = (short)f2b(x0[j]); pk[4 + j] = (short)f2b(x1[j]);
            }
            afrag[g][kc] = pk;
        }
    }
    // lanes sharing c (4 quads) cover all 128 k's
    xn2[0] += __shfl_xor(xn2[0], 16); xn2[0] += __shfl_xor(xn2[0], 32);
    xn2[1] += __shfl_xor(xn2[1], 16); xn2[1] += __shfl_xor(xn2[1], 32);

    __syncthreads();

    // ---- MFMA GEMM: Mx[32 rows][128 cols] per wave ----
    floatx4 acc[2][8];
#pragma unroll
    for (int g = 0; g < 2; ++g)
#pragma unroll
        for (int n = 0; n < 8; ++n)
            acc[g][n] = (floatx4){0.f, 0.f, 0.f, 0.f};

#pragma unroll
    for (int kc = 0; kc < 4; ++kc) {
#pragma unroll
        for (int n = 0; n < 8; ++n) {
            short8 bf = *reinterpret_cast<const short8*>(
                &ldsW[(n * 16 + c) * 136 + kc * 32 + q * 8]);
            acc[0][n] = __builtin_amdgcn_mfma_f32_16x16x32_bf16(afrag[0][kc], bf, acc[0][n], 0, 0, 0);
            acc[1][n] = __builtin_amdgcn_mfma_f32_16x16x32_bf16(afrag[1][kc], bf, acc[1][n], 0, 0, 0);
        }
    }

    // ---- fused epilogue (C layout: col = n*16+c, row = q*4+r) ----
#pragma unroll
    for (int g = 0; g < 2; ++g) {
        float m2[4], mb[4];
#pragma unroll
        for (int r = 0; r < 4; ++r) {
            float s2 = 0.f, sb = 0.f;
#pragma unroll
            for (int n = 0; n < 8; ++n) {
                float v = acc[g][n][r];
                s2 = fmaf(v, v, s2);
                sb = fmaf(v, bias_f[n], sb);
            }
            m2[r] = s2; mb[r] = sb;
        }
#pragma unroll
        for (int r = 0; r < 4; ++r) {
            m2[r] += __shfl_xor(m2[r], 1); mb[r] += __shfl_xor(mb[r], 1);
            m2[r] += __shfl_xor(m2[r], 2); mb[r] += __shfl_xor(mb[r], 2);
            m2[r] += __shfl_xor(m2[r], 4); mb[r] += __shfl_xor(mb[r], 4);
            m2[r] += __shfl_xor(m2[r], 8); mb[r] += __shfl_xor(mb[r], 8);
        }
#pragma unroll
        for (int r = 0; r < 4; ++r) {
            float xr2   = __shfl(xn2[g], q * 4 + r);          // row scalar
            float xnorm = fmaxf(sqrtf(xr2), 1e-15f);
            float u     = fminf(xnorm, 1.f - 1e-7f);
            float at    = 0.5f * __logf((1.f + u) / (1.f - u));   // artanh
            float Mxn   = fmaxf(sqrtf(m2[r]), 1e-15f);
            float arg   = Mxn / xnorm * at;                        // >= 0
            float e     = __expf(2.f * arg);
            float th    = 1.f - 2.f / (e + 1.f);                   // tanh
            float scale = (Mxn <= 1e-10f) ? 0.f : th / Mxn;
            float y2 = scale * scale * m2[r];                      // ||y||^2
            float yb = scale * mb[r];                              // y.b
            float t1  = 1.f + 2.f * yb + b2;
            float den = fmaxf(fmaf(y2, b2, 1.f + 2.f * yb), 1e-15f);
            float Af = t1 * scale / den;        // z = Af*Mx + Bf*bias
            float Bf = (1.f - y2) / den;
            float zn2 = Af * Af * m2[r] + 2.f * Af * Bf * mb[r] + Bf * Bf * b2;
            float zn  = fmaxf(sqrtf(zn2), 1e-15f);
            const float maxn = 1.f - 1e-5f;
            float fac = (zn > maxn) ? (maxn / zn) : 1.f;
            Af *= fac; Bf *= fac;

            int row = rowbase + g * 16 + q * 4 + r;
            float* orow = Out + (size_t)row * 128;
#pragma unroll
            for (int n = 0; n < 8; ++n) {
                orow[n * 16 + c] = fmaf(Af, acc[g][n][r], Bf * bias_f[n]);
            }
        }
    }
}

extern "C" void kernel_launch(void* const* d_in, const int* in_sizes, int n_in,
                              void* d_out, int out_size, void* d_ws, size_t ws_size,
                              hipStream_t stream) {
    const float* X    = (const float*)d_in[0];
    const float* W    = (const float*)d_in[1];
    const float* Bias = (const float*)d_in[2];
    float* Out = (float*)d_out;

    dim3 grid(2048), block(256);
    hipLaunchKernelGGL(mobius_linear_kernel, grid, block, 0, stream, X, W, Bias, Out);
}